// Round 9
// baseline (99.045 us; speedup 1.0000x reference)
//
#include <hip/hip_runtime.h>
#include <hip/hip_bf16.h>

// GraphSAGE 2-layer forward, fused topology + bf16 gather table:
//   k_wprep: Wt = [Wx1|Wn1] cols, bf16 hi/lo
//   k_conv:  fbf = bf16(feats)   (streaming; halves all random-gather bytes)
//   k_fused: per 16-row tile: gather f1 + mean10(f2) from fbf -> LDS -> MFMA
//            h1 = relu([f1@Wx1 ; mean10(f2)@Wn1] + b)  (bf16 out)
//   k_out:   per output row: h0, g0, normalize, FC (gathers from fbf)

typedef __bf16 bf16x8 __attribute__((ext_vector_type(8)));
typedef float  f32x4  __attribute__((ext_vector_type(4)));

constexpr int IN    = 256;
constexpr int HIDC  = 128;
constexpr int NNODE = 100000;
constexpr int ROWS1 = 512 * 25;   // 12800

// ---------------- Kernel P0: Wt = [Wx1|Wn1] columns as bf16 hi/lo -----------
__global__ __launch_bounds__(256) void k_wprep(
    const float* __restrict__ Wx, const float* __restrict__ Wn,
    __bf16* __restrict__ WtH, __bf16* __restrict__ WtL)
{
    const int j = blockIdx.x;
    const int k = threadIdx.x;
    const float v = (j < HIDC) ? Wx[(size_t)k * HIDC + j]
                               : Wn[(size_t)k * HIDC + (j - HIDC)];
    const __bf16 h = (__bf16)v;
    const __bf16 l = (__bf16)(v - (float)h);
    const size_t o = (size_t)j * IN + k;
    WtH[o] = h;
    WtL[o] = l;
}

// ---------------- Kernel V: fbf = bf16(feats), streaming --------------------
// 16 floats per thread; 512 thr; grid 3125 covers 25.6M elements exactly.
__global__ __launch_bounds__(512) void k_conv(
    const float* __restrict__ feats, __bf16* __restrict__ fbf)
{
    const size_t e = ((size_t)blockIdx.x * 512 + threadIdx.x) * 16;
    const float4* src = (const float4*)(feats + e);
    const float4 v0 = src[0], v1 = src[1], v2 = src[2], v3 = src[3];
    const bf16x8 o0 = {(__bf16)v0.x, (__bf16)v0.y, (__bf16)v0.z, (__bf16)v0.w,
                       (__bf16)v1.x, (__bf16)v1.y, (__bf16)v1.z, (__bf16)v1.w};
    const bf16x8 o1 = {(__bf16)v2.x, (__bf16)v2.y, (__bf16)v2.z, (__bf16)v2.w,
                       (__bf16)v3.x, (__bf16)v3.y, (__bf16)v3.z, (__bf16)v3.w};
    *(bf16x8*)(fbf + e)     = o0;
    *(bf16x8*)(fbf + e + 8) = o1;
}

// ---------------- Kernel F: fused gather + MFMA for h1 ----------------------
// Block = 16 rows, 512 thr = 8 waves. Wave w stages rows {2w, 2w+1}: half-wave
// hw handles row 2w+hw, lanes l32 cover the 512B bf16 row in 16B chunks —
// each wave-load fetches TWO rows (11 loads/wave vs 22 in the f32 version).
// Then wave w computes branch (w&1), col-group (w>>1)*32 via 2-pass MFMA.
__global__ __launch_bounds__(512) void k_fused(
    const int* __restrict__ ids1, const int* __restrict__ ids2,
    const __bf16* __restrict__ fbf,
    const __bf16* __restrict__ WtH, const __bf16* __restrict__ WtL,
    const float* __restrict__ bx, const float* __restrict__ bn,
    __bf16* __restrict__ h1)
{
    __shared__ __bf16 a0[16 * IN];   // f1 rows (bf16)
    __shared__ __bf16 a1[16 * IN];   // mean10(f2) rows (bf16)
    const int tid  = threadIdx.x;
    const int w    = tid >> 6;
    const int lane = tid & 63;
    const int hw   = lane >> 5;      // which row of the pair
    const int l32  = lane & 31;      // 16B chunk within the 512B row
    const int r0   = blockIdx.x * 16;

    // ---- stage: row rr = 2w + hw
    {
        const int rr   = 2 * w + hw;
        const int r    = r0 + rr;
        const int base = r * 10;
        const bf16x8 vx = *(const bf16x8*)&fbf[(size_t)ids1[r] * IN + l32 * 8];
        float s[8] = {0.f, 0.f, 0.f, 0.f, 0.f, 0.f, 0.f, 0.f};
        #pragma unroll
        for (int kk = 0; kk < 10; ++kk) {
            const bf16x8 v = *(const bf16x8*)&fbf[(size_t)ids2[base + kk] * IN + l32 * 8];
            #pragma unroll
            for (int jq = 0; jq < 8; ++jq) s[jq] += (float)v[jq];
        }
        bf16x8 mn;
        #pragma unroll
        for (int jq = 0; jq < 8; ++jq) mn[jq] = (__bf16)(s[jq] * 0.1f);

        const int e  = (rr << 8) + l32 * 8;
        const int es = e ^ ((rr & 7) << 3);        // 16B-slot XOR swizzle
        *(bf16x8*)&a0[es] = vx;
        *(bf16x8*)&a1[es] = mn;
    }
    __syncthreads();

    // ---- compute: wave w -> branch br = w&1, col-group cg = w>>1 (32 cols)
    const int br  = w & 1;
    const int cg  = w >> 1;
    const int l15 = lane & 15;
    const int lk  = lane >> 4;
    const __bf16* __restrict__ As = br ? a1 : a0;
    const __bf16* __restrict__ WH = WtH + (size_t)br * HIDC * IN;
    const __bf16* __restrict__ WL = WtL + (size_t)br * HIDC * IN;

    const f32x4 z = {0.f, 0.f, 0.f, 0.f};
    f32x4 acc[2] = {z, z};

    for (int k0 = 0; k0 < IN; k0 += 32) {
        int ea = (l15 << 8) + k0 + lk * 8;
        ea ^= (l15 & 7) << 3;
        const bf16x8 a = *(const bf16x8*)&As[ea];
        #pragma unroll
        for (int ct = 0; ct < 2; ++ct) {
            const size_t eb = (size_t)(cg * 32 + ct * 16 + l15) * IN + k0 + lk * 8;
            const bf16x8 bH = *(const bf16x8*)&WH[eb];
            const bf16x8 bL = *(const bf16x8*)&WL[eb];
            acc[ct] = __builtin_amdgcn_mfma_f32_16x16x32_bf16(a, bH, acc[ct], 0, 0, 0);
            acc[ct] = __builtin_amdgcn_mfma_f32_16x16x32_bf16(a, bL, acc[ct], 0, 0, 0);
        }
    }

    // ---- epilogue: C/D col=lane&15, row=(lane>>4)*4+reg; relu + bias, bf16
    const float* __restrict__ bias = br ? bn : bx;
    #pragma unroll
    for (int ct = 0; ct < 2; ++ct) {
        const int colL = cg * 32 + ct * 16 + l15;      // 0..127 within branch
        const float bv = bias[colL];
        #pragma unroll
        for (int q = 0; q < 4; ++q) {
            const int rr = lk * 4 + q;
            h1[(size_t)(r0 + rr) * IN + br * HIDC + colL] =
                (__bf16)fmaxf(acc[ct][q] + bv, 0.f);
        }
    }
}

// ---------------- Kernel C: per output row, 512 threads ---------------------
__global__ __launch_bounds__(512) void k_out(
    const int* __restrict__ ids, const int* __restrict__ ids1,
    const __bf16* __restrict__ fbf, const __bf16* __restrict__ h1,
    const float* __restrict__ Wx1, const float* __restrict__ bx1,
    const float* __restrict__ Wn1, const float* __restrict__ bn1,
    const float* __restrict__ Wx2, const float* __restrict__ bx2,
    const float* __restrict__ Wn2, const float* __restrict__ bn2,
    const float* __restrict__ Wfc, const float* __restrict__ bfc,
    float* __restrict__ out)
{
    __shared__ float x0[IN];
    __shared__ float m1[IN];
    __shared__ float mh[IN];
    __shared__ float h0[IN];
    __shared__ float g0[IN];
    __shared__ float partA[2][IN];
    __shared__ float partB[2][IN];
    __shared__ float red[8];
    __shared__ float fcred[7][4];
    const int i   = blockIdx.x;
    const int tid = threadIdx.x;
    const int c   = tid & 255;
    const int h   = tid >> 8;

    float s = 0.f, sh = 0.f;
    for (int kk = h; kk < 25; kk += 2) {
        const int r = i * 25 + kk;
        s  += (float)fbf[(size_t)ids1[r] * IN + c];
        sh += (float)h1[(size_t)r * IN + c];
    }
    if (h == 0) x0[c] = (float)fbf[(size_t)ids[i] * IN + c];
    partA[h][c] = s;
    partB[h][c] = sh;
    __syncthreads();
    if (h == 0) m1[c] = (partA[0][c] + partA[1][c]) * 0.04f;
    else        mh[c] = (partB[0][c] + partB[1][c]) * 0.04f;
    __syncthreads();

    const int  jj = c & 127;
    const bool nb = (c >= 128);
    {
        const float* __restrict__ W = nb ? Wn1 : Wx1;
        const float* __restrict__ X = nb ? m1 : x0;
        float acc = 0.f;
        #pragma unroll 4
        for (int k = h * 128; k < h * 128 + 128; ++k)
            acc = fmaf(X[k], W[(size_t)k * HIDC + jj], acc);
        partA[h][c] = acc;
    }
    __syncthreads();
    if (h == 0)
        h0[c] = fmaxf(partA[0][c] + partA[1][c] + (nb ? bn1 : bx1)[jj], 0.f);
    __syncthreads();
    {
        const float* __restrict__ W = nb ? Wn2 : Wx2;
        const float* __restrict__ X = nb ? mh : h0;
        float acc = 0.f;
        #pragma unroll 4
        for (int k = h * 128; k < h * 128 + 128; ++k)
            acc = fmaf(X[k], W[(size_t)k * HIDC + jj], acc);
        partB[h][c] = acc;
    }
    __syncthreads();
    if (h == 0)
        g0[c] = partB[0][c] + partB[1][c] + (nb ? bn2 : bx2)[jj];
    __syncthreads();

    {
        const float gv = g0[c];
        float sq = gv * gv;
        #pragma unroll
        for (int off = 32; off > 0; off >>= 1) sq += __shfl_down(sq, off);
        if ((tid & 63) == 0) red[tid >> 6] = sq;
    }
    __syncthreads();
    const float total = (red[0] + red[1] + red[2] + red[3] +
                         red[4] + red[5] + red[6] + red[7]) * 0.5f;
    const float inv = 1.f / fmaxf(sqrtf(total), 1e-12f);
    const float p = g0[c] * inv;

    const int qbase = h * 4;
    const int qn    = h ? 3 : 4;
    for (int q = qbase; q < qbase + qn; ++q) {
        float t = p * Wfc[(size_t)c * 7 + q];
        #pragma unroll
        for (int off = 32; off > 0; off >>= 1) t += __shfl_down(t, off);
        if ((tid & 63) == 0) fcred[q][(tid >> 6) & 3] = t;
    }
    __syncthreads();
    if (tid < 7) {
        out[(size_t)i * 7 + tid] =
            fcred[tid][0] + fcred[tid][1] + fcred[tid][2] + fcred[tid][3] + bfc[tid];
    }
}

extern "C" void kernel_launch(void* const* d_in, const int* in_sizes, int n_in,
                              void* d_out, int out_size, void* d_ws, size_t ws_size,
                              hipStream_t stream) {
    const int*   ids   = (const int*)d_in[0];
    const int*   ids1  = (const int*)d_in[1];
    const int*   ids2  = (const int*)d_in[2];
    const float* feats = (const float*)d_in[3];
    const float* Wx1   = (const float*)d_in[4];
    const float* bx1   = (const float*)d_in[5];
    const float* Wn1   = (const float*)d_in[6];
    const float* bn1   = (const float*)d_in[7];
    const float* Wx2   = (const float*)d_in[8];
    const float* bx2   = (const float*)d_in[9];
    const float* Wn2   = (const float*)d_in[10];
    const float* bn2   = (const float*)d_in[11];
    const float* Wfc   = (const float*)d_in[12];
    const float* bfc   = (const float*)d_in[13];
    float* out = (float*)d_out;

    __bf16* fbf = (__bf16*)d_ws;                      // [100000][256] bf16 = 51.2 MB
    __bf16* h1  = fbf + (size_t)NNODE * IN;           // [12800][256] bf16 = 6.55 MB
    __bf16* WtH = h1 + (size_t)ROWS1 * IN;            // [256][256] bf16
    __bf16* WtL = WtH + (size_t)IN * IN;

    k_wprep<<<256, 256, 0, stream>>>(Wx1, Wn1, WtH, WtL);
    k_conv<<<(NNODE * IN) / (512 * 16), 512, 0, stream>>>(feats, fbf);
    k_fused<<<ROWS1 / 16, 512, 0, stream>>>(ids1, ids2, fbf, WtH, WtL,
                                            bx1, bn1, h1);
    k_out<<<512, 512, 0, stream>>>(ids, ids1, fbf, h1,
                                   Wx1, bx1, Wn1, bn1,
                                   Wx2, bx2, Wn2, bn2,
                                   Wfc, bfc, out);
}

// Round 10
// 71.483 us; speedup vs baseline: 1.3856x; 1.3856x over previous
//
#include <hip/hip_runtime.h>
#include <hip/hip_bf16.h>

// GraphSAGE 2-layer forward, fused topology (round-8) + explicit-MLP staging:
//   k_wprep: Wt = [Wx1|Wn1] cols, bf16 hi/lo
//   k_fused: per 16-row tile: gather f1 + mean10(f2) -> bf16 LDS -> MFMA
//            h1 = relu([f1@Wx1 ; mean10(f2)@Wn1] + b)  (bf16 out)
//            staging loads ALL 22 float4 chunks before summing (ILP ~22)
//   k_out:   per output row: h0, g0, normalize, FC

typedef __bf16 bf16x8 __attribute__((ext_vector_type(8)));
typedef __bf16 bf16x4 __attribute__((ext_vector_type(4)));
typedef float  f32x4  __attribute__((ext_vector_type(4)));

constexpr int IN    = 256;
constexpr int HIDC  = 128;
constexpr int ROWS1 = 512 * 25;   // 12800

// ---------------- Kernel P0: Wt = [Wx1|Wn1] columns as bf16 hi/lo -----------
__global__ __launch_bounds__(256) void k_wprep(
    const float* __restrict__ Wx, const float* __restrict__ Wn,
    __bf16* __restrict__ WtH, __bf16* __restrict__ WtL)
{
    const int j = blockIdx.x;
    const int k = threadIdx.x;
    const float v = (j < HIDC) ? Wx[(size_t)k * HIDC + j]
                               : Wn[(size_t)k * HIDC + (j - HIDC)];
    const __bf16 h = (__bf16)v;
    const __bf16 l = (__bf16)(v - (float)h);
    const size_t o = (size_t)j * IN + k;
    WtH[o] = h;
    WtL[o] = l;
}

// ---------------- Kernel F: fused gather + MFMA for h1 ----------------------
// Block = 16 rows, 512 thr = 8 waves. Wave w stages rows {2w, 2w+1}; all 22
// float4 gathers are issued before any use (explicit MLP). Then wave w
// computes branch (w&1), col-group (w>>1)*32 via 2-pass MFMA.
__global__ __launch_bounds__(512) void k_fused(
    const int* __restrict__ ids1, const int* __restrict__ ids2,
    const float* __restrict__ feats,
    const __bf16* __restrict__ WtH, const __bf16* __restrict__ WtL,
    const float* __restrict__ bx, const float* __restrict__ bn,
    __bf16* __restrict__ h1)
{
    __shared__ __bf16 a0[16 * IN];   // f1 rows (bf16-hi)
    __shared__ __bf16 a1[16 * IN];   // mean10(f2) rows (bf16-hi)
    const int tid  = threadIdx.x;
    const int w    = tid >> 6;
    const int lane = tid & 63;
    const int r0   = blockIdx.x * 16;

    // ---- stage: rows rA = r0+2w, rB = r0+2w+1; issue ALL loads first
    {
        const int rA = r0 + 2 * w;
        const int rB = rA + 1;
        float4 vx0, vx1, vn0[10], vn1[10];
        vx0 = ((const float4*)(feats + (size_t)ids1[rA] * IN))[lane];
        vx1 = ((const float4*)(feats + (size_t)ids1[rB] * IN))[lane];
        #pragma unroll
        for (int kk = 0; kk < 10; ++kk)
            vn0[kk] = ((const float4*)(feats + (size_t)ids2[rA * 10 + kk] * IN))[lane];
        #pragma unroll
        for (int kk = 0; kk < 10; ++kk)
            vn1[kk] = ((const float4*)(feats + (size_t)ids2[rB * 10 + kk] * IN))[lane];

        float4 s0 = make_float4(0.f, 0.f, 0.f, 0.f);
        float4 s1 = make_float4(0.f, 0.f, 0.f, 0.f);
        #pragma unroll
        for (int kk = 0; kk < 10; ++kk) {
            s0.x += vn0[kk].x; s0.y += vn0[kk].y; s0.z += vn0[kk].z; s0.w += vn0[kk].w;
            s1.x += vn1[kk].x; s1.y += vn1[kk].y; s1.z += vn1[kk].z; s1.w += vn1[kk].w;
        }

        const int rrA = 2 * w,  rrB = 2 * w + 1;
        const int eA = (rrA << 8) + lane * 4;
        const int eB = (rrB << 8) + lane * 4;
        const int eAs = eA ^ ((rrA & 7) << 3);     // 16B-slot XOR swizzle
        const int eBs = eB ^ ((rrB & 7) << 3);
        const bf16x4 x0v = {(__bf16)vx0.x, (__bf16)vx0.y, (__bf16)vx0.z, (__bf16)vx0.w};
        const bf16x4 x1v = {(__bf16)vx1.x, (__bf16)vx1.y, (__bf16)vx1.z, (__bf16)vx1.w};
        const bf16x4 m0v = {(__bf16)(s0.x * 0.1f), (__bf16)(s0.y * 0.1f),
                            (__bf16)(s0.z * 0.1f), (__bf16)(s0.w * 0.1f)};
        const bf16x4 m1v = {(__bf16)(s1.x * 0.1f), (__bf16)(s1.y * 0.1f),
                            (__bf16)(s1.z * 0.1f), (__bf16)(s1.w * 0.1f)};
        *(bf16x4*)&a0[eAs] = x0v;
        *(bf16x4*)&a0[eBs] = x1v;
        *(bf16x4*)&a1[eAs] = m0v;
        *(bf16x4*)&a1[eBs] = m1v;
    }
    __syncthreads();

    // ---- compute: wave w -> branch br = w&1, col-group cg = w>>1 (32 cols)
    const int br  = w & 1;
    const int cg  = w >> 1;
    const int l15 = lane & 15;
    const int lk  = lane >> 4;
    const __bf16* __restrict__ As = br ? a1 : a0;
    const __bf16* __restrict__ WH = WtH + (size_t)br * HIDC * IN;
    const __bf16* __restrict__ WL = WtL + (size_t)br * HIDC * IN;

    const f32x4 z = {0.f, 0.f, 0.f, 0.f};
    f32x4 acc[2] = {z, z};

    for (int k0 = 0; k0 < IN; k0 += 32) {
        int ea = (l15 << 8) + k0 + lk * 8;
        ea ^= (l15 & 7) << 3;
        const bf16x8 a = *(const bf16x8*)&As[ea];
        #pragma unroll
        for (int ct = 0; ct < 2; ++ct) {
            const size_t eb = (size_t)(cg * 32 + ct * 16 + l15) * IN + k0 + lk * 8;
            const bf16x8 bH = *(const bf16x8*)&WH[eb];
            const bf16x8 bL = *(const bf16x8*)&WL[eb];
            acc[ct] = __builtin_amdgcn_mfma_f32_16x16x32_bf16(a, bH, acc[ct], 0, 0, 0);
            acc[ct] = __builtin_amdgcn_mfma_f32_16x16x32_bf16(a, bL, acc[ct], 0, 0, 0);
        }
    }

    // ---- epilogue: C/D col=lane&15, row=(lane>>4)*4+reg; relu + bias, bf16
    const float* __restrict__ bias = br ? bn : bx;
    #pragma unroll
    for (int ct = 0; ct < 2; ++ct) {
        const int colL = cg * 32 + ct * 16 + l15;      // 0..127 within branch
        const float bv = bias[colL];
        #pragma unroll
        for (int q = 0; q < 4; ++q) {
            const int rr = lk * 4 + q;
            h1[(size_t)(r0 + rr) * IN + br * HIDC + colL] =
                (__bf16)fmaxf(acc[ct][q] + bv, 0.f);
        }
    }
}

// ---------------- Kernel C: per output row, 512 threads ---------------------
// Half h covers rows h*13 .. h*13+12 (h=1 has 12, padded by clamp+mask).
__global__ __launch_bounds__(512) void k_out(
    const int* __restrict__ ids, const int* __restrict__ ids1,
    const float* __restrict__ feats, const __bf16* __restrict__ h1,
    const float* __restrict__ Wx1, const float* __restrict__ bx1,
    const float* __restrict__ Wn1, const float* __restrict__ bn1,
    const float* __restrict__ Wx2, const float* __restrict__ bx2,
    const float* __restrict__ Wn2, const float* __restrict__ bn2,
    const float* __restrict__ Wfc, const float* __restrict__ bfc,
    float* __restrict__ out)
{
    __shared__ float x0[IN];
    __shared__ float m1[IN];
    __shared__ float mh[IN];
    __shared__ float h0[IN];
    __shared__ float g0[IN];
    __shared__ float partA[2][IN];
    __shared__ float partB[2][IN];
    __shared__ float red[8];
    __shared__ float fcred[7][4];
    const int i   = blockIdx.x;
    const int tid = threadIdx.x;
    const int c   = tid & 255;
    const int h   = tid >> 8;

    // explicit-MLP gather of 13 feats rows + 13 h1 rows
    {
        float v1[13], v2[13];
        #pragma unroll
        for (int t = 0; t < 13; ++t) {
            const int kk = h * 13 + t;
            const int kc = kk < 25 ? kk : 24;           // clamp (mask below)
            const int r  = i * 25 + kc;
            v1[t] = feats[(size_t)ids1[r] * IN + c];
            v2[t] = (float)h1[(size_t)r * IN + c];
        }
        float s = 0.f, sh = 0.f;
        #pragma unroll
        for (int t = 0; t < 13; ++t) {
            const float msk = (h * 13 + t < 25) ? 1.f : 0.f;
            s  += msk * v1[t];
            sh += msk * v2[t];
        }
        if (h == 0) x0[c] = feats[(size_t)ids[i] * IN + c];
        partA[h][c] = s;
        partB[h][c] = sh;
    }
    __syncthreads();
    if (h == 0) m1[c] = (partA[0][c] + partA[1][c]) * 0.04f;
    else        mh[c] = (partB[0][c] + partB[1][c]) * 0.04f;
    __syncthreads();

    const int  jj = c & 127;
    const bool nb = (c >= 128);
    {
        const float* __restrict__ W = nb ? Wn1 : Wx1;
        const float* __restrict__ X = nb ? m1 : x0;
        float acc = 0.f;
        #pragma unroll 8
        for (int k = h * 128; k < h * 128 + 128; ++k)
            acc = fmaf(X[k], W[(size_t)k * HIDC + jj], acc);
        partA[h][c] = acc;
    }
    __syncthreads();
    if (h == 0)
        h0[c] = fmaxf(partA[0][c] + partA[1][c] + (nb ? bn1 : bx1)[jj], 0.f);
    __syncthreads();
    {
        const float* __restrict__ W = nb ? Wn2 : Wx2;
        const float* __restrict__ X = nb ? mh : h0;
        float acc = 0.f;
        #pragma unroll 8
        for (int k = h * 128; k < h * 128 + 128; ++k)
            acc = fmaf(X[k], W[(size_t)k * HIDC + jj], acc);
        partB[h][c] = acc;
    }
    __syncthreads();
    if (h == 0)
        g0[c] = partB[0][c] + partB[1][c] + (nb ? bn2 : bx2)[jj];
    __syncthreads();

    {
        const float gv = g0[c];
        float sq = gv * gv;
        #pragma unroll
        for (int off = 32; off > 0; off >>= 1) sq += __shfl_down(sq, off);
        if ((tid & 63) == 0) red[tid >> 6] = sq;
    }
    __syncthreads();
    const float total = (red[0] + red[1] + red[2] + red[3] +
                         red[4] + red[5] + red[6] + red[7]) * 0.5f;
    const float inv = 1.f / fmaxf(sqrtf(total), 1e-12f);
    const float p = g0[c] * inv;

    const int qbase = h * 4;
    const int qn    = h ? 3 : 4;
    for (int q = qbase; q < qbase + qn; ++q) {
        float t = p * Wfc[(size_t)c * 7 + q];
        #pragma unroll
        for (int off = 32; off > 0; off >>= 1) t += __shfl_down(t, off);
        if ((tid & 63) == 0) fcred[q][(tid >> 6) & 3] = t;
    }
    __syncthreads();
    if (tid < 7) {
        out[(size_t)i * 7 + tid] =
            fcred[tid][0] + fcred[tid][1] + fcred[tid][2] + fcred[tid][3] + bfc[tid];
    }
}

extern "C" void kernel_launch(void* const* d_in, const int* in_sizes, int n_in,
                              void* d_out, int out_size, void* d_ws, size_t ws_size,
                              hipStream_t stream) {
    const int*   ids   = (const int*)d_in[0];
    const int*   ids1  = (const int*)d_in[1];
    const int*   ids2  = (const int*)d_in[2];
    const float* feats = (const float*)d_in[3];
    const float* Wx1   = (const float*)d_in[4];
    const float* bx1   = (const float*)d_in[5];
    const float* Wn1   = (const float*)d_in[6];
    const float* bn1   = (const float*)d_in[7];
    const float* Wx2   = (const float*)d_in[8];
    const float* bx2   = (const float*)d_in[9];
    const float* Wn2   = (const float*)d_in[10];
    const float* bn2   = (const float*)d_in[11];
    const float* Wfc   = (const float*)d_in[12];
    const float* bfc   = (const float*)d_in[13];
    float* out = (float*)d_out;

    __bf16* h1  = (__bf16*)d_ws;                      // [12800][256] bf16 = 6.55 MB
    __bf16* WtH = h1 + (size_t)ROWS1 * IN;            // [256][256] bf16
    __bf16* WtL = WtH + (size_t)IN * IN;

    k_wprep<<<256, 256, 0, stream>>>(Wx1, Wn1, WtH, WtL);
    k_fused<<<ROWS1 / 16, 512, 0, stream>>>(ids1, ids2, feats, WtH, WtL,
                                            bx1, bn1, h1);
    k_out<<<512, 512, 0, stream>>>(ids, ids1, feats, h1,
                                   Wx1, bx1, Wn1, bn1,
                                   Wx2, bx2, Wn2, bn2,
                                   Wfc, bfc, out);
}

// Round 11
// 69.675 us; speedup vs baseline: 1.4215x; 1.0259x over previous
//
#include <hip/hip_runtime.h>
#include <hip/hip_bf16.h>

// GraphSAGE 2-layer forward, SPLIT topology:
//   k_wprep: Wt = [Wx1|Wn1] cols, bf16 hi/lo
//   k_gath:  one wave per sample row: gather f1 + mean10(f2) -> A0/A1 bf16
//            panels (no LDS, max occupancy -- the proven-fast gather shape)
//   k_gemm:  h1 = relu([A0@Wx1 ; A1@Wn1] + b); W fragments held in REGISTERS
//            per wave (loaded once, reused for 128 rows) -- no in-loop B loads
//   k_out:   per output row: h0, g0, normalize, FC (m1 from contiguous A0)
// Precision: A bf16, W 2-pass hi+lo MFMA (round-6/8 numerics, absmax ~1e-3).

typedef __bf16 bf16x8 __attribute__((ext_vector_type(8)));
typedef __bf16 bf16x4 __attribute__((ext_vector_type(4)));
typedef float  f32x4  __attribute__((ext_vector_type(4)));

constexpr int IN    = 256;
constexpr int HIDC  = 128;
constexpr int ROWS1 = 512 * 25;   // 12800

// ---------------- Kernel P0: Wt = [Wx1|Wn1] columns as bf16 hi/lo -----------
__global__ __launch_bounds__(256) void k_wprep(
    const float* __restrict__ Wx, const float* __restrict__ Wn,
    __bf16* __restrict__ WtH, __bf16* __restrict__ WtL)
{
    const int j = blockIdx.x;
    const int k = threadIdx.x;
    const float v = (j < HIDC) ? Wx[(size_t)k * HIDC + j]
                               : Wn[(size_t)k * HIDC + (j - HIDC)];
    const __bf16 h = (__bf16)v;
    const __bf16 l = (__bf16)(v - (float)h);
    const size_t o = (size_t)j * IN + k;
    WtH[o] = h;
    WtL[o] = l;
}

// ---------------- Kernel G: gather f1 + mean10(f2) -> bf16 panels -----------
// One wave per row r: 11 independent 1KB loads, no LDS, 8 waves/block.
__global__ __launch_bounds__(512) void k_gath(
    const int* __restrict__ ids1, const int* __restrict__ ids2,
    const float* __restrict__ feats,
    __bf16* __restrict__ A0, __bf16* __restrict__ A1)
{
    const int r    = blockIdx.x * 8 + (threadIdx.x >> 6);
    const int lane = threadIdx.x & 63;
    const int base = r * 10;

    const float4 vx = ((const float4*)(feats + (size_t)ids1[r] * IN))[lane];
    float4 s = make_float4(0.f, 0.f, 0.f, 0.f);
    #pragma unroll
    for (int kk = 0; kk < 10; ++kk) {
        const float4 v = ((const float4*)(feats + (size_t)ids2[base + kk] * IN))[lane];
        s.x += v.x; s.y += v.y; s.z += v.z; s.w += v.w;
    }
    const bf16x4 a0 = {(__bf16)vx.x, (__bf16)vx.y, (__bf16)vx.z, (__bf16)vx.w};
    const bf16x4 a1 = {(__bf16)(s.x * 0.1f), (__bf16)(s.y * 0.1f),
                       (__bf16)(s.z * 0.1f), (__bf16)(s.w * 0.1f)};
    *(bf16x4*)&A0[(size_t)r * IN + lane * 4] = a0;
    *(bf16x4*)&A1[(size_t)r * IN + lane * 4] = a1;
}

// ---------------- Kernel M: h1 via MFMA, B-in-registers ---------------------
// 1600 waves (400 blocks x 4). Wave gw: br = gw&1 (branch/panel), cg = (gw>>1)&7
// (16-col group), strip = gw>>4 (128 rows = 8 tiles of 16).
// W frags (8 k-blocks x {hi,lo} = 16 x bf16x8 = 64 VGPR) loaded ONCE per wave.
// Per tile: 8 independent A-loads (16B, k-contiguous) + 16 MFMA. No LDS.
__global__ __launch_bounds__(256) void k_gemm(
    const __bf16* __restrict__ A0, const __bf16* __restrict__ A1,
    const __bf16* __restrict__ WtH, const __bf16* __restrict__ WtL,
    const float* __restrict__ bx, const float* __restrict__ bn,
    __bf16* __restrict__ h1)
{
    const int tid  = threadIdx.x;
    const int lane = tid & 63;
    const int l15  = lane & 15;
    const int lk   = lane >> 4;
    const int gw   = blockIdx.x * 4 + (tid >> 6);
    const int br   = gw & 1;
    const int cg   = (gw >> 1) & 7;
    const int strip = gw >> 4;            // 0..99

    const __bf16* __restrict__ Ap = br ? A1 : A0;
    const int colG = br * HIDC + cg * 16 + l15;       // global col in [0,256)
    const float bv = (br ? bn : bx)[cg * 16 + l15];

    // ---- load B fragments once (col = colG, all 8 k-blocks, hi+lo)
    bf16x8 bh[8], bl[8];
    #pragma unroll
    for (int kb = 0; kb < 8; ++kb) {
        const size_t eb = (size_t)colG * IN + kb * 32 + lk * 8;
        bh[kb] = *(const bf16x8*)&WtH[eb];
        bl[kb] = *(const bf16x8*)&WtL[eb];
    }

    // ---- 8 row-tiles of 16
    #pragma unroll 2
    for (int t = 0; t < 8; ++t) {
        const int r0 = strip * 128 + t * 16;
        bf16x8 a[8];
        #pragma unroll
        for (int kb = 0; kb < 8; ++kb)
            a[kb] = *(const bf16x8*)&Ap[(size_t)(r0 + l15) * IN + kb * 32 + lk * 8];

        f32x4 acc = {0.f, 0.f, 0.f, 0.f};
        #pragma unroll
        for (int kb = 0; kb < 8; ++kb) {
            acc = __builtin_amdgcn_mfma_f32_16x16x32_bf16(a[kb], bh[kb], acc, 0, 0, 0);
            acc = __builtin_amdgcn_mfma_f32_16x16x32_bf16(a[kb], bl[kb], acc, 0, 0, 0);
        }
        // C/D: col=lane&15 (-> colG), row=(lane>>4)*4+reg
        #pragma unroll
        for (int q = 0; q < 4; ++q) {
            h1[(size_t)(r0 + lk * 4 + q) * IN + colG] =
                (__bf16)fmaxf(acc[q] + bv, 0.f);
        }
    }
}

// ---------------- Kernel C: per output row, 512 threads ---------------------
// m1 from contiguous A0 panel; x0 gathered from f32 feats; h1 bf16 panel.
__global__ __launch_bounds__(512) void k_out(
    const int* __restrict__ ids, const int* __restrict__ ids1,
    const float* __restrict__ feats,
    const __bf16* __restrict__ A0, const __bf16* __restrict__ h1,
    const float* __restrict__ Wx1, const float* __restrict__ bx1,
    const float* __restrict__ Wn1, const float* __restrict__ bn1,
    const float* __restrict__ Wx2, const float* __restrict__ bx2,
    const float* __restrict__ Wn2, const float* __restrict__ bn2,
    const float* __restrict__ Wfc, const float* __restrict__ bfc,
    float* __restrict__ out)
{
    __shared__ float x0[IN];
    __shared__ float m1[IN];
    __shared__ float mh[IN];
    __shared__ float h0[IN];
    __shared__ float g0[IN];
    __shared__ float partA[2][IN];
    __shared__ float partB[2][IN];
    __shared__ float red[8];
    __shared__ float fcred[7][4];
    const int i   = blockIdx.x;
    const int tid = threadIdx.x;
    const int c   = tid & 255;
    const int h   = tid >> 8;

    // contiguous panel reads: 13 A0 rows + 13 h1 rows per half (clamp+mask)
    {
        float v1[13], v2[13];
        #pragma unroll
        for (int t = 0; t < 13; ++t) {
            const int kk = h * 13 + t;
            const int kc = kk < 25 ? kk : 24;
            const int r  = i * 25 + kc;
            v1[t] = (float)A0[(size_t)r * IN + c];
            v2[t] = (float)h1[(size_t)r * IN + c];
        }
        float s = 0.f, sh = 0.f;
        #pragma unroll
        for (int t = 0; t < 13; ++t) {
            const float msk = (h * 13 + t < 25) ? 1.f : 0.f;
            s  += msk * v1[t];
            sh += msk * v2[t];
        }
        if (h == 0) x0[c] = feats[(size_t)ids[i] * IN + c];
        partA[h][c] = s;
        partB[h][c] = sh;
    }
    __syncthreads();
    if (h == 0) m1[c] = (partA[0][c] + partA[1][c]) * 0.04f;
    else        mh[c] = (partB[0][c] + partB[1][c]) * 0.04f;
    __syncthreads();

    const int  jj = c & 127;
    const bool nb = (c >= 128);
    {
        const float* __restrict__ W = nb ? Wn1 : Wx1;
        const float* __restrict__ X = nb ? m1 : x0;
        float acc = 0.f;
        #pragma unroll 8
        for (int k = h * 128; k < h * 128 + 128; ++k)
            acc = fmaf(X[k], W[(size_t)k * HIDC + jj], acc);
        partA[h][c] = acc;
    }
    __syncthreads();
    if (h == 0)
        h0[c] = fmaxf(partA[0][c] + partA[1][c] + (nb ? bn1 : bx1)[jj], 0.f);
    __syncthreads();
    {
        const float* __restrict__ W = nb ? Wn2 : Wx2;
        const float* __restrict__ X = nb ? mh : h0;
        float acc = 0.f;
        #pragma unroll 8
        for (int k = h * 128; k < h * 128 + 128; ++k)
            acc = fmaf(X[k], W[(size_t)k * HIDC + jj], acc);
        partB[h][c] = acc;
    }
    __syncthreads();
    if (h == 0)
        g0[c] = partB[0][c] + partB[1][c] + (nb ? bn2 : bx2)[jj];
    __syncthreads();

    {
        const float gv = g0[c];
        float sq = gv * gv;
        #pragma unroll
        for (int off = 32; off > 0; off >>= 1) sq += __shfl_down(sq, off);
        if ((tid & 63) == 0) red[tid >> 6] = sq;
    }
    __syncthreads();
    const float total = (red[0] + red[1] + red[2] + red[3] +
                         red[4] + red[5] + red[6] + red[7]) * 0.5f;
    const float inv = 1.f / fmaxf(sqrtf(total), 1e-12f);
    const float p = g0[c] * inv;

    const int qbase = h * 4;
    const int qn    = h ? 3 : 4;
    for (int q = qbase; q < qbase + qn; ++q) {
        float t = p * Wfc[(size_t)c * 7 + q];
        #pragma unroll
        for (int off = 32; off > 0; off >>= 1) t += __shfl_down(t, off);
        if ((tid & 63) == 0) fcred[q][(tid >> 6) & 3] = t;
    }
    __syncthreads();
    if (tid < 7) {
        out[(size_t)i * 7 + tid] =
            fcred[tid][0] + fcred[tid][1] + fcred[tid][2] + fcred[tid][3] + bfc[tid];
    }
}

extern "C" void kernel_launch(void* const* d_in, const int* in_sizes, int n_in,
                              void* d_out, int out_size, void* d_ws, size_t ws_size,
                              hipStream_t stream) {
    const int*   ids   = (const int*)d_in[0];
    const int*   ids1  = (const int*)d_in[1];
    const int*   ids2  = (const int*)d_in[2];
    const float* feats = (const float*)d_in[3];
    const float* Wx1   = (const float*)d_in[4];
    const float* bx1   = (const float*)d_in[5];
    const float* Wn1   = (const float*)d_in[6];
    const float* bn1   = (const float*)d_in[7];
    const float* Wx2   = (const float*)d_in[8];
    const float* bx2   = (const float*)d_in[9];
    const float* Wn2   = (const float*)d_in[10];
    const float* bn2   = (const float*)d_in[11];
    const float* Wfc   = (const float*)d_in[12];
    const float* bfc   = (const float*)d_in[13];
    float* out = (float*)d_out;

    __bf16* A0  = (__bf16*)d_ws;                      // [12800][256] bf16
    __bf16* A1  = A0  + (size_t)ROWS1 * IN;           // [12800][256] bf16
    __bf16* h1  = A1  + (size_t)ROWS1 * IN;           // [12800][256] bf16
    __bf16* WtH = h1  + (size_t)ROWS1 * IN;           // [256][256] bf16
    __bf16* WtL = WtH + (size_t)IN * IN;

    k_wprep<<<256, 256, 0, stream>>>(Wx1, Wn1, WtH, WtL);
    k_gath<<<ROWS1 / 8, 512, 0, stream>>>(ids1, ids2, feats, A0, A1);
    k_gemm<<<400, 256, 0, stream>>>(A0, A1, WtH, WtL, bx1, bn1, h1);
    k_out<<<512, 512, 0, stream>>>(ids, ids1, feats, A0, h1,
                                   Wx1, bx1, Wn1, bn1,
                                   Wx2, bx2, Wn2, bn2,
                                   Wfc, bfc, out);
}